// Round 1
// baseline (3288.868 us; speedup 1.0000x reference)
//
#include <hip/hip_runtime.h>
#include <hip/hip_bf16.h>

#define BATCH 32
#define KC 3
#define NP 512
#define FIN 64
#define FOUT 64
#define TP 64
#define COLS (FOUT*TP)   // 4096

// ---------------------------------------------------------------------------
// K1: A_eff[c,k,n,m] = cheb[k,n,m] * softmax_m(scores[b,k,n,m] + adj[n,m]*mask[k,n,m])
// one block (256 thr) per row of 512
// ---------------------------------------------------------------------------
__global__ __launch_bounds__(256) void k_softmax(
    const float* __restrict__ scores, const float* __restrict__ adj,
    const float* __restrict__ mask, const float* __restrict__ cheb,
    float* __restrict__ Aeff, int b0)
{
    const int n = blockIdx.x;
    const int k = blockIdx.y;
    const int c = blockIdx.z;
    const int b = b0 + c;
    const int tid = threadIdx.x;
    const size_t srow = (((size_t)b*KC + k)*NP + n)*NP;
    const size_t krow = ((size_t)k*NP + n)*NP;
    const size_t arow = (size_t)n*NP;

    float v0 = scores[srow+tid]     + adj[arow+tid]    *mask[krow+tid];
    float v1 = scores[srow+tid+256] + adj[arow+tid+256]*mask[krow+tid+256];

    float mx = fmaxf(v0, v1);
    #pragma unroll
    for (int off=32; off>0; off>>=1) mx = fmaxf(mx, __shfl_down(mx, off, 64));
    __shared__ float rmax[4], rsum[4];
    const int wv = tid>>6, ln = tid&63;
    if (ln==0) rmax[wv] = mx;
    __syncthreads();
    mx = fmaxf(fmaxf(rmax[0],rmax[1]), fmaxf(rmax[2],rmax[3]));

    const float e0 = __expf(v0-mx), e1 = __expf(v1-mx);
    float s = e0+e1;
    #pragma unroll
    for (int off=32; off>0; off>>=1) s += __shfl_down(s, off, 64);
    if (ln==0) rsum[wv] = s;
    __syncthreads();
    const float inv = 1.0f/(rsum[0]+rsum[1]+rsum[2]+rsum[3]);

    const size_t orow = (((size_t)c*KC + k)*NP + n)*NP;
    Aeff[orow+tid]     = cheb[krow+tid]    *e0*inv;
    Aeff[orow+tid+256] = cheb[krow+tid+256]*e1*inv;
}

// ---------------------------------------------------------------------------
// K2: W[c, k*512+m, o*64+t] = sum_i Theta[k,i,o] * x[b,m,i,t]
// block per (m,c); lane = o, wave -> 16 t's; LDS transpose for coalesced write
// ---------------------------------------------------------------------------
#define WOS 65
__global__ __launch_bounds__(256) void k_W(
    const float* __restrict__ x, const float* __restrict__ Theta,
    float* __restrict__ W, int b0)
{
    __shared__ float sm[FIN*TP + KC*FOUT*WOS];  // 4096 + 12480 floats = 66.3 KB
    float* Xm = sm;                 // [i][t]
    float* Th = sm + FIN*TP;        // [k][i][o] (12288 used)
    float* Wo = sm + FIN*TP;        // alias, reused after compute: [k][o][WOS]

    const int m = blockIdx.x, c = blockIdx.y, b = b0 + c;
    const int tid = threadIdx.x;

    const float4* xg = (const float4*)(x + (((size_t)b*NP + m)*FIN)*TP);
    #pragma unroll
    for (int j=0;j<4;j++) ((float4*)Xm)[tid + j*256] = xg[tid + j*256];
    const float4* tg = (const float4*)Theta;
    #pragma unroll
    for (int j=0;j<12;j++) ((float4*)Th)[tid + j*256] = tg[tid + j*256];
    __syncthreads();

    const int o = tid & 63, tw = tid >> 6;
    float acc[KC][16];
    #pragma unroll
    for (int k=0;k<KC;k++)
        #pragma unroll
        for (int j=0;j<16;j++) acc[k][j]=0.f;

    for (int i=0;i<FIN;i++) {
        float4 xv[4];
        #pragma unroll
        for (int q=0;q<4;q++) xv[q] = *(const float4*)&Xm[i*TP + tw*16 + q*4];
        float th[KC];
        #pragma unroll
        for (int k=0;k<KC;k++) th[k] = Th[(k*FIN + i)*FOUT + o];
        #pragma unroll
        for (int k=0;k<KC;k++) {
            #pragma unroll
            for (int q=0;q<4;q++) {
                acc[k][q*4+0] += th[k]*xv[q].x;
                acc[k][q*4+1] += th[k]*xv[q].y;
                acc[k][q*4+2] += th[k]*xv[q].z;
                acc[k][q*4+3] += th[k]*xv[q].w;
            }
        }
    }
    __syncthreads();   // everyone done reading Th/Xm before aliasing write

    #pragma unroll
    for (int k=0;k<KC;k++)
        #pragma unroll
        for (int q=0;q<4;q++)
            *(float4*)&Wo[(k*FOUT + o)*WOS + tw*16 + q*4] =
                make_float4(acc[k][q*4],acc[k][q*4+1],acc[k][q*4+2],acc[k][q*4+3]);
    __syncthreads();

    float* Wc = W + ((size_t)c*KC*NP)*COLS;
    #pragma unroll
    for (int j=0;j<12;j++) {
        int f4  = tid + j*256;      // 0..3071
        int lin = f4*4;
        int k   = lin >> 12;
        int o2  = (lin >> 6) & 63;
        int t2  = lin & 63;
        float4 v = *(const float4*)&Wo[(k*FOUT + o2)*WOS + t2];
        *(float4*)&Wc[((size_t)(k*NP + m))*COLS + (lin & 4095)] = v;
    }
}

// ---------------------------------------------------------------------------
// K3: out[b, n, col] = relu( sum_km Aeff[c,k,n,m] * W[c,km,col] )
// 128x128 tile, 8x8 microtile per thread, BK=16, fp32 VALU
// ---------------------------------------------------------------------------
#define BM 128
#define BN 128
#define BKK 16
#define ASTR 132
__global__ __launch_bounds__(256) void k_gemm(
    const float* __restrict__ Aeff, const float* __restrict__ W,
    float* __restrict__ out, int b0)
{
    __shared__ float As[BKK*ASTR];   // [kk][n-row], padded stride 132
    __shared__ float Bs[BKK*BN];     // [kk][col]

    const int n0   = blockIdx.x * BM;
    const int col0 = blockIdx.y * BN;
    const int c = blockIdx.z, b = b0 + c;
    const int tid = threadIdx.x;
    const int tx = tid & 15, ty = tid >> 4;

    float acc[8][8];
    #pragma unroll
    for (int i=0;i<8;i++)
        #pragma unroll
        for (int j=0;j<8;j++) acc[i][j]=0.f;

    const float* Ac = Aeff + ((size_t)c*KC*NP)*NP;
    const float* Wc = W    + ((size_t)c*KC*NP)*COLS;

    for (int km0=0; km0<KC*NP; km0+=BKK) {
        const int k = km0 >> 9, m0 = km0 & (NP-1);
        #pragma unroll
        for (int p=0;p<8;p++) {
            int lin = tid + p*256;
            int row = lin >> 4, kk = lin & 15;
            As[kk*ASTR + row] = Ac[((size_t)(k*NP + n0 + row))*NP + m0 + kk];
        }
        #pragma unroll
        for (int p=0;p<2;p++) {
            int f4 = tid + p*256;
            int kk = f4 >> 5, c4 = f4 & 31;
            *(float4*)&Bs[kk*BN + c4*4] =
                *(const float4*)&Wc[((size_t)(km0+kk))*COLS + col0 + c4*4];
        }
        __syncthreads();
        #pragma unroll
        for (int kk=0;kk<BKK;kk++) {
            float a[8], bb[8];
            *(float4*)&a[0]  = *(const float4*)&As[kk*ASTR + tx*8];
            *(float4*)&a[4]  = *(const float4*)&As[kk*ASTR + tx*8 + 4];
            *(float4*)&bb[0] = *(const float4*)&Bs[kk*BN + ty*8];
            *(float4*)&bb[4] = *(const float4*)&Bs[kk*BN + ty*8 + 4];
            #pragma unroll
            for (int i=0;i<8;i++)
                #pragma unroll
                for (int j=0;j<8;j++) acc[i][j] += a[i]*bb[j];
        }
        __syncthreads();
    }

    float* oc = out + ((size_t)b*NP)*COLS;
    #pragma unroll
    for (int i=0;i<8;i++) {
        float4 v0 = make_float4(fmaxf(acc[i][0],0.f), fmaxf(acc[i][1],0.f),
                                fmaxf(acc[i][2],0.f), fmaxf(acc[i][3],0.f));
        float4 v1 = make_float4(fmaxf(acc[i][4],0.f), fmaxf(acc[i][5],0.f),
                                fmaxf(acc[i][6],0.f), fmaxf(acc[i][7],0.f));
        size_t off = ((size_t)(n0 + tx*8 + i))*COLS + col0 + ty*8;
        *(float4*)&oc[off]   = v0;
        *(float4*)&oc[off+4] = v1;
    }
}

// ---------------------------------------------------------------------------
extern "C" void kernel_launch(void* const* d_in, const int* in_sizes, int n_in,
                              void* d_out, int out_size, void* d_ws, size_t ws_size,
                              hipStream_t stream)
{
    const float* x      = (const float*)d_in[0];
    const float* scores = (const float*)d_in[1];
    const float* adj    = (const float*)d_in[2];
    const float* cheb   = (const float*)d_in[3];
    const float* Theta  = (const float*)d_in[4];
    const float* mask   = (const float*)d_in[5];
    float* out = (float*)d_out;

    const size_t perA = (size_t)KC*NP*NP;     // floats: 786432  (3 MB)
    const size_t perW = (size_t)KC*NP*COLS;   // floats: 6291456 (25.2 MB)
    const size_t perB_bytes = (perA + perW)*sizeof(float);

    int C = (int)(ws_size / perB_bytes);
    if (C < 1) C = 1;
    if (C > BATCH) C = BATCH;
    while (BATCH % C) C--;                    // largest divisor of 32 that fits

    float* Aeff = (float*)d_ws;
    float* W    = Aeff + (size_t)C*perA;

    for (int b0 = 0; b0 < BATCH; b0 += C) {
        k_softmax<<<dim3(NP, KC, C), 256, 0, stream>>>(scores, adj, mask, cheb, Aeff, b0);
        k_W     <<<dim3(NP, C),      256, 0, stream>>>(x, Theta, W, b0);
        k_gemm  <<<dim3(NP/BM, COLS/BN, C), 256, 0, stream>>>(Aeff, W, out, b0);
    }
}

// Round 2
// 2114.693 us; speedup vs baseline: 1.5552x; 1.5552x over previous
//
#include <hip/hip_runtime.h>
#include <hip/hip_bf16.h>

#define BATCH 32
#define KC 3
#define NP 512
#define FIN 64
#define FOUT 64
#define TP 64
#define COLS (FOUT*TP)   // 4096
#define KDIM (KC*NP)     // 1536

typedef unsigned short ushort_t;
typedef __attribute__((ext_vector_type(8))) short short8;
typedef __attribute__((ext_vector_type(4))) float f32x4;

__device__ __forceinline__ unsigned short f2bf(float f) {
    unsigned u = __float_as_uint(f);
    return (unsigned short)((u + 0x7FFF + ((u >> 16) & 1)) >> 16);
}
__device__ __forceinline__ float bf2f(unsigned short h) {
    return __uint_as_float(((unsigned)h) << 16);
}

#define GLDS16(g, l)                                                          \
    __builtin_amdgcn_global_load_lds(                                         \
        (const __attribute__((address_space(1))) void*)(g),                   \
        (__attribute__((address_space(3))) void*)(l), 16, 0, 0)

// ---------------------------------------------------------------------------
// K1: softmax -> A_eff, emitted as bf16 hi/lo pair. Layout [c][k][n][m].
// ---------------------------------------------------------------------------
__global__ __launch_bounds__(256) void k_softmax(
    const float* __restrict__ scores, const float* __restrict__ adj,
    const float* __restrict__ mask, const float* __restrict__ cheb,
    unsigned short* __restrict__ Ah, unsigned short* __restrict__ Al, int b0)
{
    const int n = blockIdx.x;
    const int k = blockIdx.y;
    const int c = blockIdx.z;
    const int b = b0 + c;
    const int tid = threadIdx.x;
    const size_t srow = (((size_t)b*KC + k)*NP + n)*NP;
    const size_t krow = ((size_t)k*NP + n)*NP;
    const size_t arow = (size_t)n*NP;

    float v0 = scores[srow+tid]     + adj[arow+tid]    *mask[krow+tid];
    float v1 = scores[srow+tid+256] + adj[arow+tid+256]*mask[krow+tid+256];

    float mx = fmaxf(v0, v1);
    #pragma unroll
    for (int off=32; off>0; off>>=1) mx = fmaxf(mx, __shfl_down(mx, off, 64));
    __shared__ float rmax[4], rsum[4];
    const int wv = tid>>6, ln = tid&63;
    if (ln==0) rmax[wv] = mx;
    __syncthreads();
    mx = fmaxf(fmaxf(rmax[0],rmax[1]), fmaxf(rmax[2],rmax[3]));

    const float e0 = __expf(v0-mx), e1 = __expf(v1-mx);
    float s = e0+e1;
    #pragma unroll
    for (int off=32; off>0; off>>=1) s += __shfl_down(s, off, 64);
    if (ln==0) rsum[wv] = s;
    __syncthreads();
    const float inv = 1.0f/(rsum[0]+rsum[1]+rsum[2]+rsum[3]);

    const size_t orow = (((size_t)c*KC + k)*NP + n)*NP;
    float a0 = cheb[krow+tid]    *e0*inv;
    float a1 = cheb[krow+tid+256]*e1*inv;
    unsigned short h0 = f2bf(a0), h1 = f2bf(a1);
    unsigned short l0 = f2bf(a0 - bf2f(h0)), l1 = f2bf(a1 - bf2f(h1));
    Ah[orow+tid]     = h0;  Al[orow+tid]     = l0;
    Ah[orow+tid+256] = h1;  Al[orow+tid+256] = l1;
}

// ---------------------------------------------------------------------------
// K2: W[c, k*512+m, o*64+t] = sum_i Theta[k,i,o] * x[b,m,i,t]  (fp32, unchanged)
// ---------------------------------------------------------------------------
#define WOS 65
__global__ __launch_bounds__(256) void k_W(
    const float* __restrict__ x, const float* __restrict__ Theta,
    float* __restrict__ W, int b0)
{
    __shared__ float sm[FIN*TP + KC*FOUT*WOS];
    float* Xm = sm;
    float* Th = sm + FIN*TP;
    float* Wo = sm + FIN*TP;   // alias, reused after compute

    const int m = blockIdx.x, c = blockIdx.y, b = b0 + c;
    const int tid = threadIdx.x;

    const float4* xg = (const float4*)(x + (((size_t)b*NP + m)*FIN)*TP);
    #pragma unroll
    for (int j=0;j<4;j++) ((float4*)Xm)[tid + j*256] = xg[tid + j*256];
    const float4* tg = (const float4*)Theta;
    #pragma unroll
    for (int j=0;j<12;j++) ((float4*)Th)[tid + j*256] = tg[tid + j*256];
    __syncthreads();

    const int o = tid & 63, tw = tid >> 6;
    float acc[KC][16];
    #pragma unroll
    for (int k=0;k<KC;k++)
        #pragma unroll
        for (int j=0;j<16;j++) acc[k][j]=0.f;

    for (int i=0;i<FIN;i++) {
        float4 xv[4];
        #pragma unroll
        for (int q=0;q<4;q++) xv[q] = *(const float4*)&Xm[i*TP + tw*16 + q*4];
        float th[KC];
        #pragma unroll
        for (int k=0;k<KC;k++) th[k] = Th[(k*FIN + i)*FOUT + o];
        #pragma unroll
        for (int k=0;k<KC;k++) {
            #pragma unroll
            for (int q=0;q<4;q++) {
                acc[k][q*4+0] += th[k]*xv[q].x;
                acc[k][q*4+1] += th[k]*xv[q].y;
                acc[k][q*4+2] += th[k]*xv[q].z;
                acc[k][q*4+3] += th[k]*xv[q].w;
            }
        }
    }
    __syncthreads();

    #pragma unroll
    for (int k=0;k<KC;k++)
        #pragma unroll
        for (int q=0;q<4;q++)
            *(float4*)&Wo[(k*FOUT + o)*WOS + tw*16 + q*4] =
                make_float4(acc[k][q*4],acc[k][q*4+1],acc[k][q*4+2],acc[k][q*4+3]);
    __syncthreads();

    float* Wc = W + ((size_t)c*KDIM)*COLS;
    #pragma unroll
    for (int j=0;j<12;j++) {
        int f4  = tid + j*256;
        int lin = f4*4;
        int k   = lin >> 12;
        float4 v = *(const float4*)&Wo[(k*FOUT + ((lin>>6)&63))*WOS + (lin&63)];
        *(float4*)&Wc[((size_t)(k*NP + m))*COLS + (lin & 4095)] = v;
    }
}

// ---------------------------------------------------------------------------
// K2b: transpose W[km][col] fp32 -> Wt[col][km] bf16 hi/lo. 64x64 tiles.
// ---------------------------------------------------------------------------
__global__ __launch_bounds__(256) void k_trans(
    const float* __restrict__ W,
    unsigned short* __restrict__ Wth, unsigned short* __restrict__ Wtl)
{
    __shared__ float Ls[64][68];
    const int km0 = blockIdx.x*64, col0 = blockIdx.y*64, c = blockIdx.z;
    const float* Wc = W + (size_t)c*KDIM*COLS;
    const int tid = threadIdx.x;
    const int r = tid >> 4, f4 = tid & 15;
    #pragma unroll
    for (int j=0;j<4;j++) {
        float4 v = *(const float4*)&Wc[(size_t)(km0 + r + j*16)*COLS + col0 + f4*4];
        *(float4*)&Ls[r + j*16][f4*4] = v;
    }
    __syncthreads();
    const int oc = tid >> 2, seg = tid & 3;   // output row (col), km segment of 16
    unsigned short h[16], l[16];
    #pragma unroll
    for (int u=0;u<16;u++) {
        float f = Ls[seg*16 + u][oc];
        h[u] = f2bf(f);
        l[u] = f2bf(f - bf2f(h[u]));
    }
    size_t off = ((size_t)c*COLS + col0 + oc)*KDIM + km0 + seg*16;
    *(uint4*)&Wth[off]   = *(const uint4*)&h[0];
    *(uint4*)&Wth[off+8] = *(const uint4*)&h[8];
    *(uint4*)&Wtl[off]   = *(const uint4*)&l[0];
    *(uint4*)&Wtl[off+8] = *(const uint4*)&l[8];
}

// ---------------------------------------------------------------------------
// K3: bf16x3 MFMA GEMM. out[b,n,col] = relu( sum A*W ), 128x128 tile,
// 4 waves 2x2, each wave 4x4 of 16x16x32 MFMAs. 3 passes: AhWh, AlWh, AhWl.
// ---------------------------------------------------------------------------
__global__ __launch_bounds__(256) void k_gemm(
    const unsigned short* __restrict__ Ah, const unsigned short* __restrict__ Al,
    const unsigned short* __restrict__ Wth, const unsigned short* __restrict__ Wtl,
    float* __restrict__ out, int b0)
{
    __shared__ __align__(16) unsigned short As[128*32];
    __shared__ __align__(16) unsigned short Bs[128*32];

    const int tid  = threadIdx.x;
    const int lane = tid & 63, wave = tid >> 6;
    const int wr = wave >> 1, wc = wave & 1;
    const int lr = lane & 15, quad = lane >> 4;
    const int n0 = blockIdx.x * 128, col0 = blockIdx.y * 128, c = blockIdx.z;

    const size_t cA = (size_t)c * KC*NP*NP;
    const size_t cW = (size_t)c * COLS*KDIM;
    const unsigned short* Aps[3] = {Ah + cA, Al + cA, Ah + cA};
    const unsigned short* Bps[3] = {Wth + cW, Wth + cW, Wtl + cW};

    f32x4 acc[4][4];
    #pragma unroll
    for (int i=0;i<4;i++)
        #pragma unroll
        for (int j=0;j<4;j++)
            acc[i][j] = (f32x4){0.f,0.f,0.f,0.f};

    const int sr   = tid >> 2;        // staging row 0..63
    const int qoff = (tid & 3) * 8;   // element offset within 32-wide k-chunk

    unsigned short* lA0 = As + tid*8;
    unsigned short* lA1 = As + 2048 + tid*8;
    unsigned short* lB0 = Bs + tid*8;
    unsigned short* lB1 = Bs + 2048 + tid*8;

    #pragma unroll 1
    for (int p=0; p<3; p++) {
        const unsigned short* A_ = Aps[p];
        const unsigned short* B_ = Bps[p];
        #pragma unroll 1
        for (int km0=0; km0<KDIM; km0+=32) {
            const int kk = km0 >> 9, m0 = km0 & (NP-1);
            const unsigned short* ga0 = A_ + ((size_t)(kk*NP + n0 + sr))*NP + m0 + qoff;
            const unsigned short* gb0 = B_ + ((size_t)(col0 + sr))*KDIM + km0 + qoff;
            GLDS16(ga0,           lA0);
            GLDS16(ga0 + 64*NP,   lA1);
            GLDS16(gb0,           lB0);
            GLDS16(gb0 + 64*KDIM, lB1);
            __syncthreads();

            short8 af[4], bfv[4];
            #pragma unroll
            for (int i=0;i<4;i++)
                af[i] = *(const short8*)&As[(wr*64 + i*16 + lr)*32 + quad*8];
            #pragma unroll
            for (int j=0;j<4;j++)
                bfv[j] = *(const short8*)&Bs[(wc*64 + j*16 + lr)*32 + quad*8];
            #pragma unroll
            for (int i=0;i<4;i++)
                #pragma unroll
                for (int j=0;j<4;j++)
                    acc[i][j] = __builtin_amdgcn_mfma_f32_16x16x32_bf16(
                        af[i], bfv[j], acc[i][j], 0, 0, 0);
            __syncthreads();
        }
    }

    const size_t ob = ((size_t)(b0 + c)*NP + n0 + wr*64)*COLS + col0 + wc*64;
    #pragma unroll
    for (int i=0;i<4;i++) {
        #pragma unroll
        for (int r=0;r<4;r++) {
            const size_t row_off = ob + (size_t)(i*16 + quad*4 + r)*COLS;
            #pragma unroll
            for (int j=0;j<4;j++)
                out[row_off + j*16 + lr] = fmaxf(acc[i][j][r], 0.f);
        }
    }
}

// ---------------------------------------------------------------------------
extern "C" void kernel_launch(void* const* d_in, const int* in_sizes, int n_in,
                              void* d_out, int out_size, void* d_ws, size_t ws_size,
                              hipStream_t stream)
{
    const float* x      = (const float*)d_in[0];
    const float* scores = (const float*)d_in[1];
    const float* adj    = (const float*)d_in[2];
    const float* cheb   = (const float*)d_in[3];
    const float* Theta  = (const float*)d_in[4];
    const float* mask   = (const float*)d_in[5];
    float* out = (float*)d_out;

    // per-batch workspace bytes
    const size_t eA  = (size_t)KC*NP*NP;       // 786432 elems per A array
    const size_t eW  = (size_t)KDIM*COLS;      // 6291456 elems
    const size_t perB = 2*eA*2 + eW*4 + 2*eW*2;  // Ah+Al + W(fp32) + Wth+Wtl

    int C = (int)(ws_size / perB);
    if (C < 1) C = 1;
    if (C > BATCH) C = BATCH;
    while (BATCH % C) C--;

    char* p = (char*)d_ws;
    unsigned short* Ah  = (unsigned short*)p;  p += (size_t)C*eA*2;
    unsigned short* Al  = (unsigned short*)p;  p += (size_t)C*eA*2;
    unsigned short* Wth = (unsigned short*)p;  p += (size_t)C*eW*2;
    unsigned short* Wtl = (unsigned short*)p;  p += (size_t)C*eW*2;
    float*          W   = (float*)p;

    for (int b0 = 0; b0 < BATCH; b0 += C) {
        k_softmax<<<dim3(NP, KC, C), 256, 0, stream>>>(scores, adj, mask, cheb, Ah, Al, b0);
        k_W     <<<dim3(NP, C),      256, 0, stream>>>(x, Theta, W, b0);
        k_trans <<<dim3(KDIM/64, COLS/64, C), 256, 0, stream>>>(W, Wth, Wtl);
        k_gemm  <<<dim3(NP/128, COLS/128, C), 256, 0, stream>>>(Ah, Al, Wth, Wtl, out, b0);
    }
}